// Round 10
// baseline (447.391 us; speedup 1.0000x reference)
//
#include <hip/hip_runtime.h>

typedef unsigned short u16;
typedef unsigned int u32;
typedef __attribute__((ext_vector_type(8))) short bfrag;   // 8 x bf16
typedef __attribute__((ext_vector_type(4))) float f32x4;

#define SROW 1032   // padded LDS row stride (bf16 elems): 2064 B
#define ACCW 36     // sh_acc row stride in f32

__device__ __forceinline__ u16 f2bf(float x) {
    unsigned int v = __float_as_uint(x);
    return (u16)((v + 0x7FFFu + ((v >> 16) & 1u)) >> 16);   // RNE
}

// tanh(x) = 1 - 2/(e^{2x}+1): inf-safe.
__device__ __forceinline__ float fast_tanh(float x) {
    float e = __builtin_amdgcn_exp2f(x * 2.885390081777927f);
    return __builtin_fmaf(-2.0f, __builtin_amdgcn_rcpf(e + 1.0f), 1.0f);
}

// ---------------- prologue: bf16 conversions + masked diag blocks (no transpose) ----------------
// diagW[b][j][i] = Bs[32b+j][32b+i] for i<j else 0  (column of weights INTO unit j)
__global__ void ren_prologue(const float* __restrict__ Bs, const float* __restrict__ Bw,
                             const float* __restrict__ Ds, const float* __restrict__ Dw,
                             u16* __restrict__ bs16, u16* __restrict__ bw16,
                             u16* __restrict__ ds16, u16* __restrict__ dw16,
                             float* __restrict__ diagW)
{
    const int g = blockIdx.x * 256 + threadIdx.x;
    if (g < 262144) {
        const int idx = g * 4;
        const int i = idx >> 10, j = idx & 1023;
        const float4 v = *reinterpret_cast<const float4*>(Bs + idx);
        u16 o[4];
        o[0] = (j + 0 < i) ? f2bf(v.x) : (u16)0;
        o[1] = (j + 1 < i) ? f2bf(v.y) : (u16)0;
        o[2] = (j + 2 < i) ? f2bf(v.z) : (u16)0;
        o[3] = (j + 3 < i) ? f2bf(v.w) : (u16)0;
        *reinterpret_cast<uint2*>(bs16 + idx) = *reinterpret_cast<const uint2*>(o);
    } else if (g < 294912) {
        const int idx = (g - 262144) * 4;
        const float4 v = *reinterpret_cast<const float4*>(Bw + idx);
        u16 o[4] = { f2bf(v.x), f2bf(v.y), f2bf(v.z), f2bf(v.w) };
        *reinterpret_cast<uint2*>(bw16 + idx) = *reinterpret_cast<const uint2*>(o);
    } else if (g < 327680) {
        const int idx = (g - 294912) * 4;
        const float4 v = *reinterpret_cast<const float4*>(Ds + idx);
        u16 o[4] = { f2bf(v.x), f2bf(v.y), f2bf(v.z), f2bf(v.w) };
        *reinterpret_cast<uint2*>(ds16 + idx) = *reinterpret_cast<const uint2*>(o);
    } else if (g < 331776) {
        const int idx = (g - 327680) * 4;
        const float4 v = *reinterpret_cast<const float4*>(Dw + idx);
        u16 o[4] = { f2bf(v.x), f2bf(v.y), f2bf(v.z), f2bf(v.w) };
        *reinterpret_cast<uint2*>(dw16 + idx) = *reinterpret_cast<const uint2*>(o);
    } else if (g < 339968) {
        const int lin0 = (g - 331776) * 4;
        #pragma unroll
        for (int t = 0; t < 4; ++t) {
            const int idx = lin0 + t;
            const int bb = idx >> 10, j = (idx >> 5) & 31, i = idx & 31;
            diagW[idx] = (i < j) ? Bs[(size_t)(bb * 32 + j) * 1024 + (bb * 32 + i)] : 0.0f;
        }
    }
}

// ---------------- main: lane-per-unit serial + 2-wave MFMA producer ----------------
// 512 wgs x 640 threads, 16 batch rows/wg, 2 wgs/CU.
// Waves 0,1: GEMM producers (nt = wave). Waves 2-9: serial, wave w handles batch
// rows 2(w-2), 2(w-2)+1; lane = (row half)*32 + hidden unit.
__global__ __launch_bounds__(640, 5) void ren_main(
    const float* __restrict__ u,
    const u16* __restrict__ bs16, const u16* __restrict__ bw16,
    const u16* __restrict__ ds16, const u16* __restrict__ dw16,
    const float* __restrict__ diagW,
    float* __restrict__ out)
{
    __shared__ __align__(16) u16   sh_S[16 * SROW];    // s history bf16 [16][1024+pad]
    __shared__ __align__(16) float sh_acc[16 * ACCW];  // pre-activation tile [16][36]

    const int tid  = threadIdx.x;
    const int wave = tid >> 6;
    const int lane = tid & 63;
    const int lr   = lane & 15;
    const int lk8  = (lane >> 4) << 3;
    const int row0 = blockIdx.x << 4;      // 16 batch rows per wg

    // GEMM state
    const int nt = wave & 1;
    bfrag fu[4];
    f32x4 acc;

    // serial state
    const int unit  = lane & 31;
    const int rowMy = ((wave - 2) << 1) + (lane >> 5);
    const int vbase = (lane & 32) << 2;            // bpermute byte base (row half)
    const float* gw = diagW + unit * 32;           // lane's weight column, + b*1024
    f32x4 wA[8], wB[8];

    if (wave < 2) {
        const float* up = u + (size_t)(row0 + lr) * 128 + lk8;
        #pragma unroll
        for (int kk = 0; kk < 4; ++kk) {
            float4 a = *reinterpret_cast<const float4*>(up + kk * 32);
            float4 c = *reinterpret_cast<const float4*>(up + kk * 32 + 4);
            bfrag f;
            f[0] = (short)f2bf(a.x); f[1] = (short)f2bf(a.y);
            f[2] = (short)f2bf(a.z); f[3] = (short)f2bf(a.w);
            f[4] = (short)f2bf(c.x); f[5] = (short)f2bf(c.y);
            f[6] = (short)f2bf(c.z); f[7] = (short)f2bf(c.w);
            fu[kk] = f;
        }
        // block 0 pre-activations = Bu only
        acc = (f32x4){0.f, 0.f, 0.f, 0.f};
        const u16* p0 = bw16 + (size_t)((nt << 4) + lr) * 128 + lk8;
        #pragma unroll
        for (int kk = 0; kk < 4; ++kk)
            acc = __builtin_amdgcn_mfma_f32_16x16x32_bf16(fu[kk], *reinterpret_cast<const bfrag*>(p0 + kk * 32), acc, 0, 0, 0);
        const int m = (lane >> 4) << 2;
        #pragma unroll
        for (int rr = 0; rr < 4; ++rr)
            sh_acc[(m + rr) * ACCW + (nt << 4) + lr] = acc[rr];
    } else {
        #pragma unroll
        for (int q = 0; q < 8; ++q) wA[q] = *reinterpret_cast<const f32x4*>(gw + q * 4);
    }
    __syncthreads();   // acc(0) + weights(0) ready

    // serial chain for one block; wc = this block's weights, wn = next's (prefetched)
    auto serial_chain = [&](int b, f32x4 (&wc)[8], f32x4 (&wn)[8]) {
        float part = sh_acc[rowMy * ACCW + unit];
        if (b + 1 < 32) {
            const float* g2 = gw + ((b + 1) << 10);
            #pragma unroll
            for (int q = 0; q < 8; ++q) wn[q] = *reinterpret_cast<const f32x4*>(g2 + q * 4);
        }
        __builtin_amdgcn_sched_barrier(0);
        #pragma unroll
        for (int i = 0; i < 32; ++i) {
            float t = fast_tanh(part);                 // lane i's t is the real s_i
            int bi = __builtin_amdgcn_ds_bpermute(vbase + (i << 2), __float_as_int(t));
            part = __builtin_fmaf(__int_as_float(bi), wc[i >> 2][i & 3], part);
        }
        float tf = fast_tanh(part);                    // final s for my unit
        sh_S[rowMy * SROW + (b << 5) + unit] = f2bf(tf);
    };

    for (int b = 0; b < 32; ++b) {
        bfrag bfin;
        if (wave < 2) {
            if (b < 31) {
                // partial GEMM for block b+1 (kc < b) + preload finish B-frag
                const int nb = b + 1;
                const int ng = (nb << 5) + (nt << 4) + lr;
                bfin = *reinterpret_cast<const bfrag*>(bs16 + (size_t)ng * 1024 + (b << 5) + lk8);
                acc = (f32x4){0.f, 0.f, 0.f, 0.f};
                const u16* p0 = bw16 + (size_t)ng * 128 + lk8;
                #pragma unroll
                for (int kk = 0; kk < 4; ++kk)
                    acc = __builtin_amdgcn_mfma_f32_16x16x32_bf16(fu[kk], *reinterpret_cast<const bfrag*>(p0 + kk * 32), acc, 0, 0, 0);
                const u16* bsp = bs16 + (size_t)ng * 1024 + lk8;
                const u16* ssp = sh_S + lr * SROW + lk8;
                #pragma unroll 8
                for (int kc = 0; kc < b; ++kc) {
                    bfrag af = *reinterpret_cast<const bfrag*>(ssp + (kc << 5));
                    acc = __builtin_amdgcn_mfma_f32_16x16x32_bf16(af, *reinterpret_cast<const bfrag*>(bsp + (kc << 5)), acc, 0, 0, 0);
                }
            }
        } else {
            if (b & 1) serial_chain(b, wB, wA);
            else       serial_chain(b, wA, wB);
        }
        __syncthreads();   // s_b visible; partials done

        if (wave < 2 && b < 31) {
            // finish block b+1 with the fresh s_b k-slice
            bfrag af = *reinterpret_cast<const bfrag*>(sh_S + lr * SROW + (b << 5) + lk8);
            acc = __builtin_amdgcn_mfma_f32_16x16x32_bf16(af, bfin, acc, 0, 0, 0);
            const int m = (lane >> 4) << 2;
            #pragma unroll
            for (int rr = 0; rr < 4; ++rr)
                sh_acc[(m + rr) * ACCW + (nt << 4) + lr] = acc[rr];
        }
        __syncthreads();   // sh_acc ready for serial(b+1)
    }

    if (wave >= 2) return;

    // ---------------- epilogue: y = s @ Ds^T + u @ D^T  (16 x 128 per wg) ----------------
    f32x4 ey[4];
    #pragma unroll
    for (int t = 0; t < 4; ++t) ey[t] = (f32x4){0.f, 0.f, 0.f, 0.f};

    const u16* ssp = sh_S + lr * SROW + lk8;
    #pragma unroll 4
    for (int kc = 0; kc < 32; ++kc) {
        bfrag af = *reinterpret_cast<const bfrag*>(ssp + (kc << 5));
        #pragma unroll
        for (int t = 0; t < 4; ++t) {
            const int n = ((nt << 2) + t) * 16 + lr;
            bfrag bf = *reinterpret_cast<const bfrag*>(ds16 + (size_t)n * 1024 + (kc << 5) + lk8);
            ey[t] = __builtin_amdgcn_mfma_f32_16x16x32_bf16(af, bf, ey[t], 0, 0, 0);
        }
    }
    #pragma unroll
    for (int kk = 0; kk < 4; ++kk) {
        #pragma unroll
        for (int t = 0; t < 4; ++t) {
            const int n = ((nt << 2) + t) * 16 + lr;
            bfrag bf = *reinterpret_cast<const bfrag*>(dw16 + n * 128 + (kk << 5) + lk8);
            ey[t] = __builtin_amdgcn_mfma_f32_16x16x32_bf16(fu[kk], bf, ey[t], 0, 0, 0);
        }
    }
    {
        const int mbase = row0 + ((lane >> 4) << 2);
        #pragma unroll
        for (int t = 0; t < 4; ++t) {
            const int n = ((nt << 2) + t) * 16 + lr;
            #pragma unroll
            for (int rr = 0; rr < 4; ++rr)
                out[(size_t)(mbase + rr) * 128 + n] = ey[t][rr];
        }
    }
}

extern "C" void kernel_launch(void* const* d_in, const int* in_sizes, int n_in,
                              void* d_out, int out_size, void* d_ws, size_t ws_size,
                              hipStream_t stream)
{
    const float* u  = (const float*)d_in[0];   // [8192,128]
    const float* Bw = (const float*)d_in[1];   // [1024,128]
    const float* Bs = (const float*)d_in[2];   // [1024,1024]
    const float* Ds = (const float*)d_in[3];   // [128,1024]
    const float* Dw = (const float*)d_in[4];   // [128,128]
    float* out = (float*)d_out;

    u16* bs16 = (u16*)d_ws;                    // 1024*1024 bf16
    u16* bw16 = bs16 + 1024 * 1024;            // 1024*128
    u16* ds16 = bw16 + 1024 * 128;             // 128*1024
    u16* dw16 = ds16 + 128 * 1024;             // 128*128
    float* diagW = (float*)(dw16 + 128 * 128); // 32 blocks x [j][i] f32, strictly-lower masked

    ren_prologue<<<1328, 256, 0, stream>>>(Bs, Bw, Ds, Dw, bs16, bw16, ds16, dw16, diagW);
    ren_main<<<512, 640, 0, stream>>>(u, bs16, bw16, ds16, dw16, diagW, out);
}

// Round 11
// 227.800 us; speedup vs baseline: 1.9640x; 1.9640x over previous
//
#include <hip/hip_runtime.h>

typedef unsigned short u16;
typedef unsigned int u32;
typedef __attribute__((ext_vector_type(8))) short bfrag;   // 8 x bf16
typedef __attribute__((ext_vector_type(4))) float f32x4;

#define SROW 1032   // padded LDS row stride (bf16 elems): 2064 B
#define ACCW 36     // sh_acc row stride in f32

__device__ __forceinline__ u16 f2bf(float x) {
    unsigned int v = __float_as_uint(x);
    return (u16)((v + 0x7FFFu + ((v >> 16) & 1u)) >> 16);   // RNE
}

// tanh(x) = 1 - 2/(e^{2x}+1): inf-safe.
__device__ __forceinline__ float fast_tanh(float x) {
    float e = __builtin_amdgcn_exp2f(x * 2.885390081777927f);
    return __builtin_fmaf(-2.0f, __builtin_amdgcn_rcpf(e + 1.0f), 1.0f);
}

// ---------------- prologue: bf16 conversions + masked diag blocks (bf16, no transpose) ----------------
// diagW16[b][j][i] = bf16(Bs[32b+j][32b+i]) for i<j else 0  (weights INTO unit j)
__global__ void ren_prologue(const float* __restrict__ Bs, const float* __restrict__ Bw,
                             const float* __restrict__ Ds, const float* __restrict__ Dw,
                             u16* __restrict__ bs16, u16* __restrict__ bw16,
                             u16* __restrict__ ds16, u16* __restrict__ dw16,
                             u16* __restrict__ diagW16)
{
    const int g = blockIdx.x * 256 + threadIdx.x;
    if (g < 262144) {
        const int idx = g * 4;
        const int i = idx >> 10, j = idx & 1023;
        const float4 v = *reinterpret_cast<const float4*>(Bs + idx);
        u16 o[4];
        o[0] = (j + 0 < i) ? f2bf(v.x) : (u16)0;
        o[1] = (j + 1 < i) ? f2bf(v.y) : (u16)0;
        o[2] = (j + 2 < i) ? f2bf(v.z) : (u16)0;
        o[3] = (j + 3 < i) ? f2bf(v.w) : (u16)0;
        *reinterpret_cast<uint2*>(bs16 + idx) = *reinterpret_cast<const uint2*>(o);
    } else if (g < 294912) {
        const int idx = (g - 262144) * 4;
        const float4 v = *reinterpret_cast<const float4*>(Bw + idx);
        u16 o[4] = { f2bf(v.x), f2bf(v.y), f2bf(v.z), f2bf(v.w) };
        *reinterpret_cast<uint2*>(bw16 + idx) = *reinterpret_cast<const uint2*>(o);
    } else if (g < 327680) {
        const int idx = (g - 294912) * 4;
        const float4 v = *reinterpret_cast<const float4*>(Ds + idx);
        u16 o[4] = { f2bf(v.x), f2bf(v.y), f2bf(v.z), f2bf(v.w) };
        *reinterpret_cast<uint2*>(ds16 + idx) = *reinterpret_cast<const uint2*>(o);
    } else if (g < 331776) {
        const int idx = (g - 327680) * 4;
        const float4 v = *reinterpret_cast<const float4*>(Dw + idx);
        u16 o[4] = { f2bf(v.x), f2bf(v.y), f2bf(v.z), f2bf(v.w) };
        *reinterpret_cast<uint2*>(dw16 + idx) = *reinterpret_cast<const uint2*>(o);
    } else if (g < 339968) {
        const int lin0 = (g - 331776) * 4;          // u16 element index base
        u16 o[4];
        #pragma unroll
        for (int t = 0; t < 4; ++t) {
            const int idx = lin0 + t;
            const int bb = idx >> 10, j = (idx >> 5) & 31, i = idx & 31;
            o[t] = (i < j) ? f2bf(Bs[(size_t)(bb * 32 + j) * 1024 + (bb * 32 + i)]) : (u16)0;
        }
        *reinterpret_cast<uint2*>(diagW16 + lin0) = *reinterpret_cast<const uint2*>(o);
    }
}

// ---------------- main: lane-per-unit serial + 2-wave MFMA producer ----------------
// 512 wgs x 640 threads, 16 batch rows/wg, 2 wgs/CU.
// Waves 0,1: GEMM producers (nt = wave). Waves 2-9: serial, wave w handles batch
// rows 2(w-2), 2(w-2)+1; lane = (row half)*32 + hidden unit. Weights: bf16 in
// registers (dbuf, 16+16 u32), prefetched one block ahead from L2.
__global__ __launch_bounds__(640, 2) void ren_main(
    const float* __restrict__ u,
    const u16* __restrict__ bs16, const u16* __restrict__ bw16,
    const u16* __restrict__ ds16, const u16* __restrict__ dw16,
    const u16* __restrict__ diagW16,
    float* __restrict__ out)
{
    __shared__ __align__(16) u16   sh_S[16 * SROW];    // s history bf16 [16][1024+pad]
    __shared__ __align__(16) float sh_acc[16 * ACCW];  // pre-activation tile [16][36]

    const int tid  = threadIdx.x;
    const int wave = tid >> 6;
    const int lane = tid & 63;
    const int lr   = lane & 15;
    const int lk8  = (lane >> 4) << 3;
    const int row0 = blockIdx.x << 4;      // 16 batch rows per wg

    // GEMM state
    const int nt = wave & 1;
    bfrag fu[4];
    f32x4 acc;

    // serial state
    const int unit  = lane & 31;
    const int rowMy = ((wave - 2) << 1) + (lane >> 5);
    const int vbase = (lane & 32) << 2;            // bpermute byte base (row half)
    const u16* gw = diagW16 + unit * 32;           // lane's weight column; + b*1024
    u32 wA[16], wB[16];

    if (wave < 2) {
        const float* up = u + (size_t)(row0 + lr) * 128 + lk8;
        #pragma unroll
        for (int kk = 0; kk < 4; ++kk) {
            float4 a = *reinterpret_cast<const float4*>(up + kk * 32);
            float4 c = *reinterpret_cast<const float4*>(up + kk * 32 + 4);
            bfrag f;
            f[0] = (short)f2bf(a.x); f[1] = (short)f2bf(a.y);
            f[2] = (short)f2bf(a.z); f[3] = (short)f2bf(a.w);
            f[4] = (short)f2bf(c.x); f[5] = (short)f2bf(c.y);
            f[6] = (short)f2bf(c.z); f[7] = (short)f2bf(c.w);
            fu[kk] = f;
        }
        // block 0 pre-activations = Bu only
        acc = (f32x4){0.f, 0.f, 0.f, 0.f};
        const u16* p0 = bw16 + (size_t)((nt << 4) + lr) * 128 + lk8;
        #pragma unroll
        for (int kk = 0; kk < 4; ++kk)
            acc = __builtin_amdgcn_mfma_f32_16x16x32_bf16(fu[kk], *reinterpret_cast<const bfrag*>(p0 + kk * 32), acc, 0, 0, 0);
        const int m = (lane >> 4) << 2;
        #pragma unroll
        for (int rr = 0; rr < 4; ++rr)
            sh_acc[(m + rr) * ACCW + (nt << 4) + lr] = acc[rr];
    } else {
        const uint4* g0 = reinterpret_cast<const uint4*>(gw);
        #pragma unroll
        for (int q = 0; q < 4; ++q) {
            uint4 v = g0[q];
            wA[4*q+0] = v.x; wA[4*q+1] = v.y; wA[4*q+2] = v.z; wA[4*q+3] = v.w;
        }
    }
    __syncthreads();   // acc(0) + weights(0) ready

    // serial chain for one block; wc = this block's weights, wn = next's (prefetched)
    auto serial_chain = [&](int b, u32 (&wc)[16], u32 (&wn)[16]) {
        float part = sh_acc[rowMy * ACCW + unit];
        if (b + 1 < 32) {
            const uint4* g2 = reinterpret_cast<const uint4*>(gw + ((b + 1) << 10));
            #pragma unroll
            for (int q = 0; q < 4; ++q) {
                uint4 v = g2[q];
                wn[4*q+0] = v.x; wn[4*q+1] = v.y; wn[4*q+2] = v.z; wn[4*q+3] = v.w;
            }
        }
        __builtin_amdgcn_sched_barrier(0);
        #pragma unroll
        for (int i = 0; i < 32; ++i) {
            float t = fast_tanh(part);                 // lane i's t is the real s_i
            int bi = __builtin_amdgcn_ds_bpermute(vbase + (i << 2), __float_as_int(t));
            u32 d = wc[i >> 1];
            u32 wbits = (i & 1) ? (d & 0xffff0000u) : (d << 16);   // bf16 -> f32 bits
            part = __builtin_fmaf(__int_as_float(bi), __uint_as_float(wbits), part);
        }
        float tf = fast_tanh(part);                    // final s for my unit
        sh_S[rowMy * SROW + (b << 5) + unit] = f2bf(tf);
    };

    for (int b = 0; b < 32; ++b) {
        bfrag bfin;
        if (wave < 2) {
            if (b < 31) {
                // partial GEMM for block b+1 (kc < b) + preload finish B-frag
                const int nb = b + 1;
                const int ng = (nb << 5) + (nt << 4) + lr;
                bfin = *reinterpret_cast<const bfrag*>(bs16 + (size_t)ng * 1024 + (b << 5) + lk8);
                acc = (f32x4){0.f, 0.f, 0.f, 0.f};
                const u16* p0 = bw16 + (size_t)ng * 128 + lk8;
                #pragma unroll
                for (int kk = 0; kk < 4; ++kk)
                    acc = __builtin_amdgcn_mfma_f32_16x16x32_bf16(fu[kk], *reinterpret_cast<const bfrag*>(p0 + kk * 32), acc, 0, 0, 0);
                const u16* bsp = bs16 + (size_t)ng * 1024 + lk8;
                const u16* ssp = sh_S + lr * SROW + lk8;
                #pragma unroll 8
                for (int kc = 0; kc < b; ++kc) {
                    bfrag af = *reinterpret_cast<const bfrag*>(ssp + (kc << 5));
                    acc = __builtin_amdgcn_mfma_f32_16x16x32_bf16(af, *reinterpret_cast<const bfrag*>(bsp + (kc << 5)), acc, 0, 0, 0);
                }
            }
        } else {
            if (b & 1) serial_chain(b, wB, wA);
            else       serial_chain(b, wA, wB);
        }
        __syncthreads();   // s_b visible; partials done

        if (wave < 2 && b < 31) {
            // finish block b+1 with the fresh s_b k-slice
            bfrag af = *reinterpret_cast<const bfrag*>(sh_S + lr * SROW + (b << 5) + lk8);
            acc = __builtin_amdgcn_mfma_f32_16x16x32_bf16(af, bfin, acc, 0, 0, 0);
            const int m = (lane >> 4) << 2;
            #pragma unroll
            for (int rr = 0; rr < 4; ++rr)
                sh_acc[(m + rr) * ACCW + (nt << 4) + lr] = acc[rr];
        }
        __syncthreads();   // sh_acc ready for serial(b+1)
    }

    if (wave >= 2) return;

    // ---------------- epilogue: y = s @ Ds^T + u @ D^T  (16 x 128 per wg) ----------------
    f32x4 ey[4];
    #pragma unroll
    for (int t = 0; t < 4; ++t) ey[t] = (f32x4){0.f, 0.f, 0.f, 0.f};

    const u16* ssp = sh_S + lr * SROW + lk8;
    #pragma unroll 4
    for (int kc = 0; kc < 32; ++kc) {
        bfrag af = *reinterpret_cast<const bfrag*>(ssp + (kc << 5));
        #pragma unroll
        for (int t = 0; t < 4; ++t) {
            const int n = ((nt << 2) + t) * 16 + lr;
            bfrag bf = *reinterpret_cast<const bfrag*>(ds16 + (size_t)n * 1024 + (kc << 5) + lk8);
            ey[t] = __builtin_amdgcn_mfma_f32_16x16x32_bf16(af, bf, ey[t], 0, 0, 0);
        }
    }
    #pragma unroll
    for (int kk = 0; kk < 4; ++kk) {
        #pragma unroll
        for (int t = 0; t < 4; ++t) {
            const int n = ((nt << 2) + t) * 16 + lr;
            bfrag bf = *reinterpret_cast<const bfrag*>(dw16 + n * 128 + (kk << 5) + lk8);
            ey[t] = __builtin_amdgcn_mfma_f32_16x16x32_bf16(fu[kk], bf, ey[t], 0, 0, 0);
        }
    }
    {
        const int mbase = row0 + ((lane >> 4) << 2);
        #pragma unroll
        for (int t = 0; t < 4; ++t) {
            const int n = ((nt << 2) + t) * 16 + lr;
            #pragma unroll
            for (int rr = 0; rr < 4; ++rr)
                out[(size_t)(mbase + rr) * 128 + n] = ey[t][rr];
        }
    }
}

extern "C" void kernel_launch(void* const* d_in, const int* in_sizes, int n_in,
                              void* d_out, int out_size, void* d_ws, size_t ws_size,
                              hipStream_t stream)
{
    const float* u  = (const float*)d_in[0];   // [8192,128]
    const float* Bw = (const float*)d_in[1];   // [1024,128]
    const float* Bs = (const float*)d_in[2];   // [1024,1024]
    const float* Ds = (const float*)d_in[3];   // [128,1024]
    const float* Dw = (const float*)d_in[4];   // [128,128]
    float* out = (float*)d_out;

    u16* bs16 = (u16*)d_ws;                    // 1024*1024 bf16
    u16* bw16 = bs16 + 1024 * 1024;            // 1024*128
    u16* ds16 = bw16 + 1024 * 128;             // 128*1024
    u16* dw16 = ds16 + 128 * 1024;             // 128*128
    u16* diagW16 = dw16 + 128 * 128;           // 32 blocks x [j][i] bf16, strictly-lower masked

    ren_prologue<<<1328, 256, 0, stream>>>(Bs, Bw, Ds, Dw, bs16, bw16, ds16, dw16, diagW16);
    ren_main<<<512, 640, 0, stream>>>(u, bs16, bw16, ds16, dw16, diagW16, out);
}

// Round 12
// 227.438 us; speedup vs baseline: 1.9671x; 1.0016x over previous
//
#include <hip/hip_runtime.h>

typedef unsigned short u16;
typedef unsigned int u32;
typedef __attribute__((ext_vector_type(8))) short bfrag;   // 8 x bf16
typedef __attribute__((ext_vector_type(4))) float f32x4;

#define SROW 1032   // padded LDS row stride (bf16 elems): 2064 B
#define ACCW 36     // sh_acc row stride in f32

__device__ __forceinline__ u16 f2bf(float x) {
    unsigned int v = __float_as_uint(x);
    return (u16)((v + 0x7FFFu + ((v >> 16) & 1u)) >> 16);   // RNE
}

// tanh(x) = 1 - 2/(e^{2x}+1): inf-safe.
__device__ __forceinline__ float fast_tanh(float x) {
    float e = __builtin_amdgcn_exp2f(x * 2.885390081777927f);
    return __builtin_fmaf(-2.0f, __builtin_amdgcn_rcpf(e + 1.0f), 1.0f);
}

// ---------------- prologue: bf16 conversions + masked diag blocks (bf16, no transpose) ----------------
// diagW16[b][j][i] = bf16(Bs[32b+j][32b+i]) for i<j else 0  (weights INTO unit j)
__global__ void ren_prologue(const float* __restrict__ Bs, const float* __restrict__ Bw,
                             const float* __restrict__ Ds, const float* __restrict__ Dw,
                             u16* __restrict__ bs16, u16* __restrict__ bw16,
                             u16* __restrict__ ds16, u16* __restrict__ dw16,
                             u16* __restrict__ diagW16)
{
    const int g = blockIdx.x * 256 + threadIdx.x;
    if (g < 262144) {
        const int idx = g * 4;
        const int i = idx >> 10, j = idx & 1023;
        const float4 v = *reinterpret_cast<const float4*>(Bs + idx);
        u16 o[4];
        o[0] = (j + 0 < i) ? f2bf(v.x) : (u16)0;
        o[1] = (j + 1 < i) ? f2bf(v.y) : (u16)0;
        o[2] = (j + 2 < i) ? f2bf(v.z) : (u16)0;
        o[3] = (j + 3 < i) ? f2bf(v.w) : (u16)0;
        *reinterpret_cast<uint2*>(bs16 + idx) = *reinterpret_cast<const uint2*>(o);
    } else if (g < 294912) {
        const int idx = (g - 262144) * 4;
        const float4 v = *reinterpret_cast<const float4*>(Bw + idx);
        u16 o[4] = { f2bf(v.x), f2bf(v.y), f2bf(v.z), f2bf(v.w) };
        *reinterpret_cast<uint2*>(bw16 + idx) = *reinterpret_cast<const uint2*>(o);
    } else if (g < 327680) {
        const int idx = (g - 294912) * 4;
        const float4 v = *reinterpret_cast<const float4*>(Ds + idx);
        u16 o[4] = { f2bf(v.x), f2bf(v.y), f2bf(v.z), f2bf(v.w) };
        *reinterpret_cast<uint2*>(ds16 + idx) = *reinterpret_cast<const uint2*>(o);
    } else if (g < 331776) {
        const int idx = (g - 327680) * 4;
        const float4 v = *reinterpret_cast<const float4*>(Dw + idx);
        u16 o[4] = { f2bf(v.x), f2bf(v.y), f2bf(v.z), f2bf(v.w) };
        *reinterpret_cast<uint2*>(dw16 + idx) = *reinterpret_cast<const uint2*>(o);
    } else if (g < 339968) {
        const int lin0 = (g - 331776) * 4;          // u16 element index base
        u16 o[4];
        #pragma unroll
        for (int t = 0; t < 4; ++t) {
            const int idx = lin0 + t;
            const int bb = idx >> 10, j = (idx >> 5) & 31, i = idx & 31;
            o[t] = (i < j) ? f2bf(Bs[(size_t)(bb * 32 + j) * 1024 + (bb * 32 + i)]) : (u16)0;
        }
        *reinterpret_cast<uint2*>(diagW16 + lin0) = *reinterpret_cast<const uint2*>(o);
    }
}

// ---------------- main: lane-per-unit serial + 2-wave MFMA producer ----------------
// 512 wgs x 640 threads, 16 batch rows/wg.
// Waves 0,1: GEMM producers (nt = wave). Waves 2-9: serial, wave w handles batch
// rows 2(w-2), 2(w-2)+1; lane = (row half)*32 + hidden unit. Weights: bf16 in
// registers (dbuf, 16+16 u32). Cross-lane s broadcast via v_readlane (constant
// lane index under full unroll) — VALU latency, not DS-pipe latency.
__global__ __launch_bounds__(640, 2) void ren_main(
    const float* __restrict__ u,
    const u16* __restrict__ bs16, const u16* __restrict__ bw16,
    const u16* __restrict__ ds16, const u16* __restrict__ dw16,
    const u16* __restrict__ diagW16,
    float* __restrict__ out)
{
    __shared__ __align__(16) u16   sh_S[16 * SROW];    // s history bf16 [16][1024+pad]
    __shared__ __align__(16) float sh_acc[16 * ACCW];  // pre-activation tile [16][36]

    const int tid  = threadIdx.x;
    const int wave = tid >> 6;
    const int lane = tid & 63;
    const int lr   = lane & 15;
    const int lk8  = (lane >> 4) << 3;
    const int row0 = blockIdx.x << 4;      // 16 batch rows per wg

    // GEMM state
    const int nt = wave & 1;
    bfrag fu[4];
    f32x4 acc;

    // serial state
    const int unit  = lane & 31;
    const int rowMy = ((wave - 2) << 1) + (lane >> 5);
    const bool hiHalf = (lane & 32) != 0;          // row-B half of the wave
    const u16* gw = diagW16 + unit * 32;           // lane's weight column; + b*1024
    u32 wA[16], wB[16];

    if (wave < 2) {
        const float* up = u + (size_t)(row0 + lr) * 128 + lk8;
        #pragma unroll
        for (int kk = 0; kk < 4; ++kk) {
            float4 a = *reinterpret_cast<const float4*>(up + kk * 32);
            float4 c = *reinterpret_cast<const float4*>(up + kk * 32 + 4);
            bfrag f;
            f[0] = (short)f2bf(a.x); f[1] = (short)f2bf(a.y);
            f[2] = (short)f2bf(a.z); f[3] = (short)f2bf(a.w);
            f[4] = (short)f2bf(c.x); f[5] = (short)f2bf(c.y);
            f[6] = (short)f2bf(c.z); f[7] = (short)f2bf(c.w);
            fu[kk] = f;
        }
        // block 0 pre-activations = Bu only
        acc = (f32x4){0.f, 0.f, 0.f, 0.f};
        const u16* p0 = bw16 + (size_t)((nt << 4) + lr) * 128 + lk8;
        #pragma unroll
        for (int kk = 0; kk < 4; ++kk)
            acc = __builtin_amdgcn_mfma_f32_16x16x32_bf16(fu[kk], *reinterpret_cast<const bfrag*>(p0 + kk * 32), acc, 0, 0, 0);
        const int m = (lane >> 4) << 2;
        #pragma unroll
        for (int rr = 0; rr < 4; ++rr)
            sh_acc[(m + rr) * ACCW + (nt << 4) + lr] = acc[rr];
    } else {
        const uint4* g0 = reinterpret_cast<const uint4*>(gw);
        #pragma unroll
        for (int q = 0; q < 4; ++q) {
            uint4 v = g0[q];
            wA[4*q+0] = v.x; wA[4*q+1] = v.y; wA[4*q+2] = v.z; wA[4*q+3] = v.w;
        }
    }
    __syncthreads();   // acc(0) + weights(0) ready

    // serial chain for one block; wc = this block's weights, wn = next's (prefetched)
    auto serial_chain = [&](int b, u32 (&wc)[16], u32 (&wn)[16]) {
        float part = sh_acc[rowMy * ACCW + unit];
        if (b + 1 < 32) {
            const uint4* g2 = reinterpret_cast<const uint4*>(gw + ((b + 1) << 10));
            #pragma unroll
            for (int q = 0; q < 4; ++q) {
                uint4 v = g2[q];
                wn[4*q+0] = v.x; wn[4*q+1] = v.y; wn[4*q+2] = v.z; wn[4*q+3] = v.w;
            }
        }
        __builtin_amdgcn_s_setprio(1);
        #pragma unroll
        for (int i = 0; i < 32; ++i) {
            int ti = __float_as_int(fast_tanh(part));        // lane i: the real s_i
            int sa = __builtin_amdgcn_readlane(ti, i);       // row A's s_i
            int sb = __builtin_amdgcn_readlane(ti, i + 32);  // row B's s_i
            float sv = __int_as_float(hiHalf ? sb : sa);
            u32 d = wc[i >> 1];
            u32 wbits = (i & 1) ? (d & 0xffff0000u) : (d << 16);   // bf16 -> f32 bits
            part = __builtin_fmaf(sv, __uint_as_float(wbits), part);
        }
        __builtin_amdgcn_s_setprio(0);
        float tf = fast_tanh(part);                    // final s for my unit
        sh_S[rowMy * SROW + (b << 5) + unit] = f2bf(tf);
    };

    for (int b = 0; b < 32; ++b) {
        bfrag bfin;
        if (wave < 2) {
            if (b < 31) {
                // partial GEMM for block b+1 (kc < b) + preload finish B-frag
                const int nb = b + 1;
                const int ng = (nb << 5) + (nt << 4) + lr;
                bfin = *reinterpret_cast<const bfrag*>(bs16 + (size_t)ng * 1024 + (b << 5) + lk8);
                acc = (f32x4){0.f, 0.f, 0.f, 0.f};
                const u16* p0 = bw16 + (size_t)ng * 128 + lk8;
                #pragma unroll
                for (int kk = 0; kk < 4; ++kk)
                    acc = __builtin_amdgcn_mfma_f32_16x16x32_bf16(fu[kk], *reinterpret_cast<const bfrag*>(p0 + kk * 32), acc, 0, 0, 0);
                const u16* bsp = bs16 + (size_t)ng * 1024 + lk8;
                const u16* ssp = sh_S + lr * SROW + lk8;
                #pragma unroll 8
                for (int kc = 0; kc < b; ++kc) {
                    bfrag af = *reinterpret_cast<const bfrag*>(ssp + (kc << 5));
                    acc = __builtin_amdgcn_mfma_f32_16x16x32_bf16(af, *reinterpret_cast<const bfrag*>(bsp + (kc << 5)), acc, 0, 0, 0);
                }
            }
        } else {
            if (b & 1) serial_chain(b, wB, wA);
            else       serial_chain(b, wA, wB);
        }
        __syncthreads();   // s_b visible; partials done

        if (wave < 2 && b < 31) {
            // finish block b+1 with the fresh s_b k-slice
            bfrag af = *reinterpret_cast<const bfrag*>(sh_S + lr * SROW + (b << 5) + lk8);
            acc = __builtin_amdgcn_mfma_f32_16x16x32_bf16(af, bfin, acc, 0, 0, 0);
            const int m = (lane >> 4) << 2;
            #pragma unroll
            for (int rr = 0; rr < 4; ++rr)
                sh_acc[(m + rr) * ACCW + (nt << 4) + lr] = acc[rr];
        }
        __syncthreads();   // sh_acc ready for serial(b+1)
    }

    if (wave >= 2) return;

    // ---------------- epilogue: y = s @ Ds^T + u @ D^T  (16 x 128 per wg) ----------------
    f32x4 ey[4];
    #pragma unroll
    for (int t = 0; t < 4; ++t) ey[t] = (f32x4){0.f, 0.f, 0.f, 0.f};

    const u16* ssp = sh_S + lr * SROW + lk8;
    #pragma unroll 4
    for (int kc = 0; kc < 32; ++kc) {
        bfrag af = *reinterpret_cast<const bfrag*>(ssp + (kc << 5));
        #pragma unroll
        for (int t = 0; t < 4; ++t) {
            const int n = ((nt << 2) + t) * 16 + lr;
            bfrag bf = *reinterpret_cast<const bfrag*>(ds16 + (size_t)n * 1024 + (kc << 5) + lk8);
            ey[t] = __builtin_amdgcn_mfma_f32_16x16x32_bf16(af, bf, ey[t], 0, 0, 0);
        }
    }
    #pragma unroll
    for (int kk = 0; kk < 4; ++kk) {
        #pragma unroll
        for (int t = 0; t < 4; ++t) {
            const int n = ((nt << 2) + t) * 16 + lr;
            bfrag bf = *reinterpret_cast<const bfrag*>(dw16 + n * 128 + (kk << 5) + lk8);
            ey[t] = __builtin_amdgcn_mfma_f32_16x16x32_bf16(fu[kk], bf, ey[t], 0, 0, 0);
        }
    }
    {
        const int mbase = row0 + ((lane >> 4) << 2);
        #pragma unroll
        for (int t = 0; t < 4; ++t) {
            const int n = ((nt << 2) + t) * 16 + lr;
            #pragma unroll
            for (int rr = 0; rr < 4; ++rr)
                out[(size_t)(mbase + rr) * 128 + n] = ey[t][rr];
        }
    }
}

extern "C" void kernel_launch(void* const* d_in, const int* in_sizes, int n_in,
                              void* d_out, int out_size, void* d_ws, size_t ws_size,
                              hipStream_t stream)
{
    const float* u  = (const float*)d_in[0];   // [8192,128]
    const float* Bw = (const float*)d_in[1];   // [1024,128]
    const float* Bs = (const float*)d_in[2];   // [1024,1024]
    const float* Ds = (const float*)d_in[3];   // [128,1024]
    const float* Dw = (const float*)d_in[4];   // [128,128]
    float* out = (float*)d_out;

    u16* bs16 = (u16*)d_ws;                    // 1024*1024 bf16
    u16* bw16 = bs16 + 1024 * 1024;            // 1024*128
    u16* ds16 = bw16 + 1024 * 128;             // 128*1024
    u16* dw16 = ds16 + 128 * 1024;             // 128*128
    u16* diagW16 = dw16 + 128 * 128;           // 32 blocks x [j][i] bf16, strictly-lower masked

    ren_prologue<<<1328, 256, 0, stream>>>(Bs, Bw, Ds, Dw, bs16, bw16, ds16, dw16, diagW16);
    ren_main<<<512, 640, 0, stream>>>(u, bs16, bw16, ds16, dw16, diagW16, out);
}

// Round 13
// 216.458 us; speedup vs baseline: 2.0669x; 1.0507x over previous
//
#include <hip/hip_runtime.h>

typedef unsigned short u16;
typedef unsigned int u32;
typedef __attribute__((ext_vector_type(8))) short bfrag;   // 8 x bf16
typedef __attribute__((ext_vector_type(4))) float f32x4;

#define SROW 1032   // padded LDS row stride (bf16 elems): 2064 B
#define ACCW 36     // sh_acc row stride in f32

__device__ __forceinline__ u16 f2bf(float x) {
    unsigned int v = __float_as_uint(x);
    return (u16)((v + 0x7FFFu + ((v >> 16) & 1u)) >> 16);   // RNE
}

// Rational tanh (XLA coefficients): float-accurate on [-9,9], only ONE
// transcendental (v_rcp) on the dependency chain — no v_exp.
__device__ __forceinline__ float tanh_r(float x) {
    x = fminf(9.0f, fmaxf(-9.0f, x));
    float x2 = x * x;
    float x4 = x2 * x2;
    float x8 = x4 * x4;
    float p01 = __builtin_fmaf(x2, 6.37261928875436e-04f, 4.89352455891786e-03f);
    float p23 = __builtin_fmaf(x2, 5.12229709037114e-08f, 1.48572235717979e-05f);
    float p45 = __builtin_fmaf(x2, 2.00018790482477e-13f, -8.60467152213735e-11f);
    float pA  = __builtin_fmaf(x4, p23, p01);
    float pB  = __builtin_fmaf(x4, -2.76076847742355e-16f, p45);
    float P   = __builtin_fmaf(x8, pB, pA);
    float q01 = __builtin_fmaf(x2, 2.26843463243900e-03f, 4.89352518554385e-03f);
    float q23 = __builtin_fmaf(x2, 1.19825839466702e-06f, 1.18534705686654e-04f);
    float Q   = __builtin_fmaf(x4, q23, q01);
    return (x * P) * __builtin_amdgcn_rcpf(Q);
}

// ---------------- prologue: bf16 conversions + masked diag blocks (bf16) ----------------
// diagW16[b][j][i] = bf16(Bs[32b+j][32b+i]) for i<j else 0  (weights INTO unit j)
__global__ void ren_prologue(const float* __restrict__ Bs, const float* __restrict__ Bw,
                             const float* __restrict__ Ds, const float* __restrict__ Dw,
                             u16* __restrict__ bs16, u16* __restrict__ bw16,
                             u16* __restrict__ ds16, u16* __restrict__ dw16,
                             u16* __restrict__ diagW16)
{
    const int g = blockIdx.x * 256 + threadIdx.x;
    if (g < 262144) {
        const int idx = g * 4;
        const int i = idx >> 10, j = idx & 1023;
        const float4 v = *reinterpret_cast<const float4*>(Bs + idx);
        u16 o[4];
        o[0] = (j + 0 < i) ? f2bf(v.x) : (u16)0;
        o[1] = (j + 1 < i) ? f2bf(v.y) : (u16)0;
        o[2] = (j + 2 < i) ? f2bf(v.z) : (u16)0;
        o[3] = (j + 3 < i) ? f2bf(v.w) : (u16)0;
        *reinterpret_cast<uint2*>(bs16 + idx) = *reinterpret_cast<const uint2*>(o);
    } else if (g < 294912) {
        const int idx = (g - 262144) * 4;
        const float4 v = *reinterpret_cast<const float4*>(Bw + idx);
        u16 o[4] = { f2bf(v.x), f2bf(v.y), f2bf(v.z), f2bf(v.w) };
        *reinterpret_cast<uint2*>(bw16 + idx) = *reinterpret_cast<const uint2*>(o);
    } else if (g < 327680) {
        const int idx = (g - 294912) * 4;
        const float4 v = *reinterpret_cast<const float4*>(Ds + idx);
        u16 o[4] = { f2bf(v.x), f2bf(v.y), f2bf(v.z), f2bf(v.w) };
        *reinterpret_cast<uint2*>(ds16 + idx) = *reinterpret_cast<const uint2*>(o);
    } else if (g < 331776) {
        const int idx = (g - 327680) * 4;
        const float4 v = *reinterpret_cast<const float4*>(Dw + idx);
        u16 o[4] = { f2bf(v.x), f2bf(v.y), f2bf(v.z), f2bf(v.w) };
        *reinterpret_cast<uint2*>(dw16 + idx) = *reinterpret_cast<const uint2*>(o);
    } else if (g < 339968) {
        const int lin0 = (g - 331776) * 4;          // u16 element index base
        u16 o[4];
        #pragma unroll
        for (int t = 0; t < 4; ++t) {
            const int idx = lin0 + t;
            const int bb = idx >> 10, j = (idx >> 5) & 31, i = idx & 31;
            o[t] = (i < j) ? f2bf(Bs[(size_t)(bb * 32 + j) * 1024 + (bb * 32 + i)]) : (u16)0;
        }
        *reinterpret_cast<uint2*>(diagW16 + lin0) = *reinterpret_cast<const uint2*>(o);
    }
}

// ---------------- main: lane-per-unit serial + 4-wave MFMA producer, single pass ----------------
// 256 wgs x 768 threads, 32 batch rows/wg -> one pass over the batch.
// Waves 0-3: GEMM producers (2x2 tile, mt=(wave>>1)&1, nt=wave&1).
// Waves 4-11: serial; wave w owns rows base..base+3 (base=(w-4)*4) as TWO
// chain-sets: chain0 = rows base,base+1 (lo/hi half-wave), chain1 = rows
// base+2,base+3. lane = unit (0-31) + half*32. Weights: bf16 in registers.
__global__ __launch_bounds__(768, 1) void ren_main(
    const float* __restrict__ u,
    const u16* __restrict__ bs16, const u16* __restrict__ bw16,
    const u16* __restrict__ ds16, const u16* __restrict__ dw16,
    const u16* __restrict__ diagW16,
    float* __restrict__ out)
{
    __shared__ __align__(16) u16   sh_S[32 * SROW];    // s history bf16 [32][1024+pad]
    __shared__ __align__(16) float sh_acc[32 * ACCW];  // pre-activation tile [32][36]

    const int tid  = threadIdx.x;
    const int wave = tid >> 6;
    const int lane = tid & 63;
    const int lr   = lane & 15;
    const int lk8  = (lane >> 4) << 3;
    const int row0 = blockIdx.x << 5;      // 32 batch rows per wg

    // GEMM state
    const int mt = (wave >> 1) & 1;
    const int nt = wave & 1;
    bfrag fu[4];
    f32x4 acc;

    // serial state
    const int unit  = lane & 31;
    const int half  = lane >> 5;
    const bool hiHalf = (half != 0);
    const int base  = (wave - 4) << 2;
    const u16* gw = diagW16 + unit * 32;   // lane's weight column; + b*1024
    u32 wA[16], wB[16];

    if (wave < 4) {
        const float* up = u + (size_t)(row0 + mt * 16 + lr) * 128 + lk8;
        #pragma unroll
        for (int kk = 0; kk < 4; ++kk) {
            float4 a = *reinterpret_cast<const float4*>(up + kk * 32);
            float4 c = *reinterpret_cast<const float4*>(up + kk * 32 + 4);
            bfrag f;
            f[0] = (short)f2bf(a.x); f[1] = (short)f2bf(a.y);
            f[2] = (short)f2bf(a.z); f[3] = (short)f2bf(a.w);
            f[4] = (short)f2bf(c.x); f[5] = (short)f2bf(c.y);
            f[6] = (short)f2bf(c.z); f[7] = (short)f2bf(c.w);
            fu[kk] = f;
        }
        // block 0 pre-activations = Bu only (each wave: its 16x16 quadrant)
        acc = (f32x4){0.f, 0.f, 0.f, 0.f};
        const u16* p0 = bw16 + (size_t)((nt << 4) + lr) * 128 + lk8;
        #pragma unroll
        for (int kk = 0; kk < 4; ++kk)
            acc = __builtin_amdgcn_mfma_f32_16x16x32_bf16(fu[kk], *reinterpret_cast<const bfrag*>(p0 + kk * 32), acc, 0, 0, 0);
        const int m = (mt << 4) + ((lane >> 4) << 2);
        #pragma unroll
        for (int rr = 0; rr < 4; ++rr)
            sh_acc[(m + rr) * ACCW + (nt << 4) + lr] = acc[rr];
    } else {
        const uint4* g0 = reinterpret_cast<const uint4*>(gw);
        #pragma unroll
        for (int q = 0; q < 4; ++q) {
            uint4 v = g0[q];
            wA[4*q+0] = v.x; wA[4*q+1] = v.y; wA[4*q+2] = v.z; wA[4*q+3] = v.w;
        }
    }
    __syncthreads();   // acc(0) + weights(0) ready

    // dual-chain serial for one block; wc = this block's weights, wn = next's
    auto serial_chain = [&](int b, u32 (&wc)[16], u32 (&wn)[16]) {
        float p0 = sh_acc[(base + half) * ACCW + unit];
        float p1 = sh_acc[(base + 2 + half) * ACCW + unit];
        if (b + 1 < 32) {
            const uint4* g2 = reinterpret_cast<const uint4*>(gw + ((b + 1) << 10));
            #pragma unroll
            for (int q = 0; q < 4; ++q) {
                uint4 v = g2[q];
                wn[4*q+0] = v.x; wn[4*q+1] = v.y; wn[4*q+2] = v.z; wn[4*q+3] = v.w;
            }
        }
        __builtin_amdgcn_s_setprio(1);
        #pragma unroll
        for (int i = 0; i < 32; ++i) {
            int t0 = __float_as_int(tanh_r(p0));             // lane i: true s_i (chain 0)
            int t1 = __float_as_int(tanh_r(p1));             // lane i: true s_i (chain 1)
            int a0 = __builtin_amdgcn_readlane(t0, i);       // row base+0
            int b0 = __builtin_amdgcn_readlane(t0, i + 32);  // row base+1
            int a1 = __builtin_amdgcn_readlane(t1, i);       // row base+2
            int b1 = __builtin_amdgcn_readlane(t1, i + 32);  // row base+3
            float s0 = __int_as_float(hiHalf ? b0 : a0);
            float s1 = __int_as_float(hiHalf ? b1 : a1);
            u32 d = wc[i >> 1];
            u32 wbits = (i & 1) ? (d & 0xffff0000u) : (d << 16);   // bf16 -> f32 bits
            float wf = __uint_as_float(wbits);
            p0 = __builtin_fmaf(s0, wf, p0);
            p1 = __builtin_fmaf(s1, wf, p1);
        }
        __builtin_amdgcn_s_setprio(0);
        sh_S[(base + half) * SROW + (b << 5) + unit]     = f2bf(tanh_r(p0));
        sh_S[(base + 2 + half) * SROW + (b << 5) + unit] = f2bf(tanh_r(p1));
    };

    for (int b = 0; b < 32; ++b) {
        bfrag bfin;
        if (wave < 4) {
            if (b < 31) {
                // partial GEMM for block b+1 (kc < b) + preload finish B-frag
                const int nb = b + 1;
                const int ng = (nb << 5) + (nt << 4) + lr;
                bfin = *reinterpret_cast<const bfrag*>(bs16 + (size_t)ng * 1024 + (b << 5) + lk8);
                acc = (f32x4){0.f, 0.f, 0.f, 0.f};
                const u16* p0 = bw16 + (size_t)ng * 128 + lk8;
                #pragma unroll
                for (int kk = 0; kk < 4; ++kk)
                    acc = __builtin_amdgcn_mfma_f32_16x16x32_bf16(fu[kk], *reinterpret_cast<const bfrag*>(p0 + kk * 32), acc, 0, 0, 0);
                const u16* bsp = bs16 + (size_t)ng * 1024 + lk8;
                const u16* ssp = sh_S + ((mt << 4) + lr) * SROW + lk8;
                #pragma unroll 8
                for (int kc = 0; kc < b; ++kc) {
                    bfrag af = *reinterpret_cast<const bfrag*>(ssp + (kc << 5));
                    acc = __builtin_amdgcn_mfma_f32_16x16x32_bf16(af, *reinterpret_cast<const bfrag*>(bsp + (kc << 5)), acc, 0, 0, 0);
                }
            }
        } else {
            if (b & 1) serial_chain(b, wB, wA);
            else       serial_chain(b, wA, wB);
        }
        __syncthreads();   // s_b visible; partials done

        if (wave < 4 && b < 31) {
            // finish block b+1 with the fresh s_b k-slice
            const u16* ssp = sh_S + ((mt << 4) + lr) * SROW + lk8;
            bfrag af = *reinterpret_cast<const bfrag*>(ssp + (b << 5));
            acc = __builtin_amdgcn_mfma_f32_16x16x32_bf16(af, bfin, acc, 0, 0, 0);
            const int m = (mt << 4) + ((lane >> 4) << 2);
            #pragma unroll
            for (int rr = 0; rr < 4; ++rr)
                sh_acc[(m + rr) * ACCW + (nt << 4) + lr] = acc[rr];
        }
        __syncthreads();   // sh_acc ready for serial(b+1)
    }

    if (wave >= 4) return;

    // ---------------- epilogue: y = s @ Ds^T + u @ D^T  (32 x 128 per wg) ----------------
    f32x4 ey[4];
    #pragma unroll
    for (int t = 0; t < 4; ++t) ey[t] = (f32x4){0.f, 0.f, 0.f, 0.f};

    const u16* ssp = sh_S + ((mt << 4) + lr) * SROW + lk8;
    #pragma unroll 4
    for (int kc = 0; kc < 32; ++kc) {
        bfrag af = *reinterpret_cast<const bfrag*>(ssp + (kc << 5));
        #pragma unroll
        for (int t = 0; t < 4; ++t) {
            const int n = ((nt << 2) + t) * 16 + lr;
            bfrag bf = *reinterpret_cast<const bfrag*>(ds16 + (size_t)n * 1024 + (kc << 5) + lk8);
            ey[t] = __builtin_amdgcn_mfma_f32_16x16x32_bf16(af, bf, ey[t], 0, 0, 0);
        }
    }
    #pragma unroll
    for (int kk = 0; kk < 4; ++kk) {
        #pragma unroll
        for (int t = 0; t < 4; ++t) {
            const int n = ((nt << 2) + t) * 16 + lr;
            bfrag bf = *reinterpret_cast<const bfrag*>(dw16 + n * 128 + (kk << 5) + lk8);
            ey[t] = __builtin_amdgcn_mfma_f32_16x16x32_bf16(fu[kk], bf, ey[t], 0, 0, 0);
        }
    }
    {
        const int mbase = row0 + (mt << 4) + ((lane >> 4) << 2);
        #pragma unroll
        for (int t = 0; t < 4; ++t) {
            const int n = ((nt << 2) + t) * 16 + lr;
            #pragma unroll
            for (int rr = 0; rr < 4; ++rr)
                out[(size_t)(mbase + rr) * 128 + n] = ey[t][rr];
        }
    }
}

extern "C" void kernel_launch(void* const* d_in, const int* in_sizes, int n_in,
                              void* d_out, int out_size, void* d_ws, size_t ws_size,
                              hipStream_t stream)
{
    const float* u  = (const float*)d_in[0];   // [8192,128]
    const float* Bw = (const float*)d_in[1];   // [1024,128]
    const float* Bs = (const float*)d_in[2];   // [1024,1024]
    const float* Ds = (const float*)d_in[3];   // [128,1024]
    const float* Dw = (const float*)d_in[4];   // [128,128]
    float* out = (float*)d_out;

    u16* bs16 = (u16*)d_ws;                    // 1024*1024 bf16
    u16* bw16 = bs16 + 1024 * 1024;            // 1024*128
    u16* ds16 = bw16 + 1024 * 128;             // 128*1024
    u16* dw16 = ds16 + 128 * 1024;             // 128*128
    u16* diagW16 = dw16 + 128 * 128;           // 32 blocks x [j][i] bf16, strictly-lower masked

    ren_prologue<<<1328, 256, 0, stream>>>(Bs, Bw, Ds, Dw, bs16, bw16, ds16, dw16, diagW16);
    ren_main<<<256, 768, 0, stream>>>(u, bs16, bw16, ds16, dw16, diagW16, out);
}